// Round 1
// baseline (2462.863 us; speedup 1.0000x reference)
//
#include <hip/hip_runtime.h>
#include <math.h>

#define TT 16
#define HH 112
#define WD 112
#define CC 96
#define NHEADS 3
#define HD 32
#define NN 98          // window tokens 2*7*7
#define NWIN 2048      // 8*16*16
#define NTOK 200704    // T*H*W == NWIN*NN
#define MLPH 384

// ---------------- K1: LN1 + shifted window gather + QKV + attention ----------------
__global__ __launch_bounds__(256) void attn_kernel(
    const float* __restrict__ x, const float* __restrict__ g1, const float* __restrict__ b1,
    const float* __restrict__ qkv_w, const float* __restrict__ qkv_b,
    const float* __restrict__ rpb, float* __restrict__ att)
{
  __shared__ float sX[NN * CC];   // 37632 B
  __shared__ float sK[NN * HD];   // 12544 B
  __shared__ float sV[NN * HD];   // 12544 B
  __shared__ int   sReg[NN];

  const int tid  = threadIdx.x;
  const int widx = blockIdx.x;
  const int head = blockIdx.y;
  const int ww = widx & 15, hw = (widx >> 4) & 15, tw = widx >> 8;

  // phase 1: gather rolled window into LDS (xs[ts,hs,ws] = xn[(ts+1)%T,(hs+3)%H,(ws+3)%W])
  for (int e = tid; e < NN * CC; e += 256) {
    int n = e / CC, c = e - n * CC;
    int it = n / 49, r = n - it * 49, ih = r / 7, iw = r - ih * 7;
    int t = tw * 2 + it + 1; if (t >= TT) t -= TT;
    int h = hw * 7 + ih + 3; if (h >= HH) h -= HH;
    int w = ww * 7 + iw + 3; if (w >= WD) w -= WD;
    sX[e] = x[((size_t)(t * HH + h) * WD + w) * CC + c];
  }
  if (tid < NN) {
    int n = tid;
    int it = n / 49, r = n - it * 49, ih = r / 7, iw = r - ih * 7;
    int ts = tw * 2 + it, hs = hw * 7 + ih, ws2 = ww * 7 + iw;
    int rt = ts < TT - 2 ? 0 : (ts < TT - 1 ? 1 : 2);
    int rh = hs < HH - 7 ? 0 : (hs < HH - 3 ? 1 : 2);
    int rw = ws2 < WD - 7 ? 0 : (ws2 < WD - 3 ? 1 : 2);
    sReg[n] = rt * 9 + rh * 3 + rw;
  }
  __syncthreads();

  // phase 2: LayerNorm per token (in place)
  if (tid < NN) {
    float mu = 0.f;
    for (int c = 0; c < CC; ++c) mu += sX[tid * CC + c];
    mu *= (1.f / CC);
    float var = 0.f;
    for (int c = 0; c < CC; ++c) { float d = sX[tid * CC + c] - mu; var += d * d; }
    var *= (1.f / CC);
    float inv = rsqrtf(var + 1e-5f);
    for (int c = 0; c < CC; ++c)
      sX[tid * CC + c] = (sX[tid * CC + c] - mu) * inv * g1[c] + b1[c];
  }
  __syncthreads();

  // phase 3: K and V for this head into LDS
  for (int e = tid; e < 2 * NN * HD; e += 256) {
    int m3 = e / (NN * HD);            // 0 -> K, 1 -> V
    int r = e - m3 * (NN * HD);
    int n = r / HD, d = r - n * HD;
    int col = (m3 + 1) * CC + head * HD + d;
    float a = qkv_b[col];
    const float* xr = &sX[n * CC];
    for (int c = 0; c < CC; ++c) a += xr[c] * qkv_w[c * (3 * CC) + col];
    if (m3 == 0) sK[n * HD + d] = a; else sV[n * HD + d] = a;
  }
  __syncthreads();

  // phase 4+5: per-row q (registers) + online softmax + PV
  if (tid < NN) {
    const int n = tid;
    const int itn = n / 49; int rr = n - itn * 49;
    const int ihn = rr / 7; const int iwn = rr - ihn * 7;

    float qreg[HD];
    {
      float qa[HD];
      #pragma unroll
      for (int d = 0; d < HD; ++d) qa[d] = qkv_b[head * HD + d];
      const float* xr = &sX[n * CC];
      for (int c = 0; c < CC; ++c) {
        float xv = xr[c];
        const float* wr = &qkv_w[c * (3 * CC) + head * HD];
        #pragma unroll
        for (int d = 0; d < HD; ++d) qa[d] += xv * wr[d];
      }
      const float scale = 0.17677669529663687f;  // 32^-0.5
      #pragma unroll
      for (int d = 0; d < HD; ++d) qreg[d] = qa[d] * scale;
    }

    const int regn = sReg[n];
    float mx = -1e30f, sum = 0.f;
    float acc[HD];
    #pragma unroll
    for (int d = 0; d < HD; ++d) acc[d] = 0.f;

    for (int m = 0; m < NN; ++m) {
      float s = 0.f;
      const float* kr = &sK[m * HD];
      #pragma unroll
      for (int d = 0; d < HD; ++d) s += qreg[d] * kr[d];
      int itm = m / 49, r2 = m - itm * 49, ihm = r2 / 7, iwm = r2 - ihm * 7;
      int ridx = (itn - itm + 1) * 169 + (ihn - ihm + 6) * 13 + (iwn - iwm + 6);
      s += rpb[ridx * NHEADS + head];
      if (regn != sReg[m]) s -= 100.f;
      if (s > mx) {
        float rsc = expf(mx - s);
        sum *= rsc;
        #pragma unroll
        for (int d = 0; d < HD; ++d) acc[d] *= rsc;
        mx = s;
      }
      float p = expf(s - mx);
      sum += p;
      const float* vr = &sV[m * HD];
      #pragma unroll
      for (int d = 0; d < HD; ++d) acc[d] += p * vr[d];
    }
    float inv = 1.f / sum;
    float* dst = att + ((size_t)(widx * NN + n)) * CC + head * HD;
    #pragma unroll
    for (int d = 0; d < HD; ++d) dst[d] = acc[d] * inv;
  }
}

// ---------------- K2: proj + reverse window + un-roll + shortcut residual ----------------
__global__ __launch_bounds__(256) void proj_kernel(
    const float* __restrict__ att, const float* __restrict__ proj_w, const float* __restrict__ proj_b,
    const float* __restrict__ x, float* __restrict__ x1)
{
  __shared__ float sA[8 * CC];
  const int tid = threadIdx.x;
  const int base = blockIdx.x * 8;    // window-token index
  for (int e = tid; e < 8 * CC; e += 256) sA[e] = att[(size_t)base * CC + e];
  __syncthreads();
  for (int e = tid; e < 8 * CC; e += 256) {
    int lt = e / CC, c = e - lt * CC;
    float a = proj_b[c];
    const float* ar = &sA[lt * CC];
    for (int j = 0; j < CC; ++j) a += ar[j] * proj_w[j * CC + c];
    int tok = base + lt;
    int widx = tok / NN, n = tok - widx * NN;
    int ww = widx & 15, hw = (widx >> 4) & 15, tw = widx >> 8;
    int it = n / 49, r = n - it * 49, ih = r / 7, iw = r - ih * 7;
    int t = tw * 2 + it + 1; if (t >= TT) t -= TT;
    int h = hw * 7 + ih + 3; if (h >= HH) h -= HH;
    int w = ww * 7 + iw + 3; if (w >= WD) w -= WD;
    size_t off = ((size_t)(t * HH + h) * WD + w) * CC + c;
    x1[off] = x[off] + a;
  }
}

// ---------------- K3: LN2 + FC1 + exact GELU + FC2 + residual ----------------
#define MTOK 16
__global__ __launch_bounds__(384) void mlp_kernel(
    const float* __restrict__ x1, const float* __restrict__ g2, const float* __restrict__ b2,
    const float* __restrict__ fc1_w, const float* __restrict__ fc1_b,
    const float* __restrict__ fc2_w, const float* __restrict__ fc2_b,
    float* __restrict__ out)
{
  __shared__ float sRow[MTOK * CC];
  __shared__ float sXn[MTOK * CC];
  __shared__ float sH[MTOK * MLPH];
  __shared__ float sMu[MTOK], sInv[MTOK];
  const int tid = threadIdx.x;
  const size_t base = (size_t)blockIdx.x * MTOK;

  for (int e = tid; e < MTOK * CC; e += 384) sRow[e] = x1[base * CC + e];
  __syncthreads();

  if (tid < MTOK) {
    float mu = 0.f;
    for (int c = 0; c < CC; ++c) mu += sRow[tid * CC + c];
    mu *= (1.f / CC);
    float var = 0.f;
    for (int c = 0; c < CC; ++c) { float d = sRow[tid * CC + c] - mu; var += d * d; }
    var *= (1.f / CC);
    sMu[tid] = mu;
    sInv[tid] = rsqrtf(var + 1e-5f);
  }
  __syncthreads();

  for (int e = tid; e < MTOK * CC; e += 384) {
    int t2 = e / CC, c = e - t2 * CC;
    sXn[e] = (sRow[e] - sMu[t2]) * sInv[t2] * g2[c] + b2[c];
  }
  __syncthreads();

  // FC1 + GELU: thread = hidden unit j
  {
    float acc[MTOK];
    #pragma unroll
    for (int t = 0; t < MTOK; ++t) acc[t] = 0.f;
    for (int c = 0; c < CC; ++c) {
      float wv = fc1_w[c * MLPH + tid];
      #pragma unroll
      for (int t = 0; t < MTOK; ++t) acc[t] += sXn[t * CC + c] * wv;
    }
    float bj = fc1_b[tid];
    #pragma unroll
    for (int t = 0; t < MTOK; ++t) {
      float v = acc[t] + bj;
      sH[t * MLPH + tid] = 0.5f * v * (1.f + erff(v * 0.70710678118654752f));
    }
  }
  __syncthreads();

  // FC2 + residual: c = tid % 96, token group = tid / 96 (4 tokens each)
  {
    int c = tid % CC, grp = tid / CC;
    float acc[4] = {0.f, 0.f, 0.f, 0.f};
    for (int j = 0; j < MLPH; ++j) {
      float wv = fc2_w[j * CC + c];
      #pragma unroll
      for (int t = 0; t < 4; ++t) acc[t] += sH[(grp * 4 + t) * MLPH + j] * wv;
    }
    float bc = fc2_b[c];
    #pragma unroll
    for (int t = 0; t < 4; ++t) {
      int tt = grp * 4 + t;
      out[(base + tt) * CC + c] = sRow[tt * CC + c] + acc[t] + bc;
    }
  }
}

extern "C" void kernel_launch(void* const* d_in, const int* in_sizes, int n_in,
                              void* d_out, int out_size, void* d_ws, size_t ws_size,
                              hipStream_t stream) {
  const float* x      = (const float*)d_in[0];
  const float* g1     = (const float*)d_in[1];
  const float* b1     = (const float*)d_in[2];
  const float* qkv_w  = (const float*)d_in[3];
  const float* qkv_b  = (const float*)d_in[4];
  const float* rpb    = (const float*)d_in[5];
  const float* proj_w = (const float*)d_in[6];
  const float* proj_b = (const float*)d_in[7];
  const float* g2     = (const float*)d_in[8];
  const float* b2     = (const float*)d_in[9];
  const float* fc1_w  = (const float*)d_in[10];
  const float* fc1_b  = (const float*)d_in[11];
  const float* fc2_w  = (const float*)d_in[12];
  const float* fc2_b  = (const float*)d_in[13];

  float* att = (float*)d_ws;                      // NTOK*96 floats
  float* x1  = att + (size_t)NTOK * CC;           // NTOK*96 floats

  attn_kernel<<<dim3(NWIN, NHEADS), 256, 0, stream>>>(x, g1, b1, qkv_w, qkv_b, rpb, att);
  proj_kernel<<<NTOK / 8, 256, 0, stream>>>(att, proj_w, proj_b, x, x1);
  mlp_kernel<<<NTOK / MTOK, 384, 0, stream>>>(x1, g2, b2, fc1_w, fc1_b, fc2_w, fc2_b, (float*)d_out);
}